// Round 1
// 2000.877 us; speedup vs baseline: 2.0610x; 2.0610x over previous
//
#include <hip/hip_runtime.h>
#include <hip/hip_bf16.h>
#include <cstdint>
#include <cstddef>

// ---------------------------------------------------------------------------
// GPT-2 forward (L=4, B=2, T=1024, C=768, H=12, V=50257) on gfx950.
// Strategy: bf16 MFMA GEMMs (fp32 accum), fp32 residual stream, flash-style
// MFMA attention with online softmax.
// ---------------------------------------------------------------------------

typedef __bf16 bf16x8 __attribute__((ext_vector_type(8)));
typedef float floatx4 __attribute__((ext_vector_type(4)));

__device__ inline float bf2f(uint16_t h) {
    union { uint32_t u; float f; } x; x.u = ((uint32_t)h) << 16; return x.f;
}
__device__ inline uint16_t f2bf(float f) {
    union { float f; uint32_t u; } x; x.f = f;
    uint32_t u = x.u;
    uint32_t r = (u + 0x7fffu + ((u >> 16) & 1u)) >> 16;   // RNE
    return (uint16_t)r;
}

// ---------------------------------------------------------------------------
// Weight transpose + fp32->bf16 convert: in fp32 [K,N] -> out bf16 [Npad,K].
// Zero-fills n in [N, Npad). blockIdx.z = layer.
// ---------------------------------------------------------------------------
__global__ void transpose_cvt(const float* __restrict__ in, uint16_t* __restrict__ out,
                              int K, int N, size_t in_lstride, size_t out_lstride) {
    __shared__ float tile[32][33];
    in  += (size_t)blockIdx.z * in_lstride;
    out += (size_t)blockIdx.z * out_lstride;
    int n0 = blockIdx.x * 32, k0 = blockIdx.y * 32;
    int tx = threadIdx.x, ty = threadIdx.y;
#pragma unroll
    for (int i = 0; i < 4; ++i) {
        int k = k0 + ty + i * 8;
        int n = n0 + tx;
        tile[ty + i * 8][tx] = (n < N) ? in[(size_t)k * N + n] : 0.f;
    }
    __syncthreads();
#pragma unroll
    for (int i = 0; i < 4; ++i) {
        int n = n0 + ty + i * 8;
        int k = k0 + tx;
        out[(size_t)n * K + k] = f2bf(tile[tx][ty + i * 8]);
    }
}

// ---------------------------------------------------------------------------
// Embedding: x[row,c] = wte[idx[row],c] + wpe[row%1024,c]   (fp32)
// ---------------------------------------------------------------------------
__global__ void embed_kernel(const int* __restrict__ idx, const float* __restrict__ wte,
                             const float* __restrict__ wpe, float* __restrict__ x) {
    int tid = blockIdx.x * 256 + threadIdx.x;      // 2048*768 total
    int row = tid / 768, c = tid - row * 768;
    int t = row & 1023;
    int tok = idx[row];
    x[tid] = wte[(size_t)tok * 768 + c] + wpe[(size_t)t * 768 + c];
}

// ---------------------------------------------------------------------------
// LayerNorm: fp32 [row,768] -> bf16 out. One block (256 thr) per row.
// ---------------------------------------------------------------------------
__global__ __launch_bounds__(256) void ln_kernel(const float* __restrict__ x,
                                                 const float* __restrict__ g,
                                                 const float* __restrict__ beta,
                                                 uint16_t* __restrict__ out) {
    int row = blockIdx.x;
    int t = threadIdx.x;
    int w = t >> 6, lane = t & 63;
    const float* xr = x + (size_t)row * 768;
    float v0 = xr[t], v1 = xr[t + 256], v2 = xr[t + 512];
    float s = v0 + v1 + v2;
    float s2 = v0 * v0 + v1 * v1 + v2 * v2;
#pragma unroll
    for (int mk = 32; mk >= 1; mk >>= 1) {
        s += __shfl_xor(s, mk, 64);
        s2 += __shfl_xor(s2, mk, 64);
    }
    __shared__ float rs[4], rq[4];
    if (lane == 0) { rs[w] = s; rq[w] = s2; }
    __syncthreads();
    float S = rs[0] + rs[1] + rs[2] + rs[3];
    float S2 = rq[0] + rq[1] + rq[2] + rq[3];
    float mean = S * (1.f / 768.f);
    float var = S2 * (1.f / 768.f) - mean * mean;
    float rinv = rsqrtf(var + 1e-5f);
    uint16_t* orow = out + (size_t)row * 768;
    orow[t]       = f2bf((v0 - mean) * rinv * g[t]       + beta[t]);
    orow[t + 256] = f2bf((v1 - mean) * rinv * g[t + 256] + beta[t + 256]);
    orow[t + 512] = f2bf((v2 - mean) * rinv * g[t + 512] + beta[t + 512]);
}

// ---------------------------------------------------------------------------
// GEMM: C[M,N] = A[M,K](bf16) @ Bt[N,K](bf16, pre-transposed) + bias.
// 128x128 tile, BK=32, 4 waves (2x2), 64x64 per wave via 4x4 mfma 16x16x32.
// Epilogues: 0=bf16 store, 1=gelu+bf16, 2=residual fp32 +=, 3=fp32 store (n<Nstore).
// ---------------------------------------------------------------------------
enum { EPI_BF16 = 0, EPI_GELU = 1, EPI_RESID = 2, EPI_F32 = 3 };

template <int EPI>
__global__ __launch_bounds__(256, 2)
void gemm128(const uint16_t* __restrict__ A, const uint16_t* __restrict__ Bt,
             const float* __restrict__ bias, uint16_t* __restrict__ Cbf,
             float* __restrict__ Cf, int M, int N, int K, int Nstore) {
    __shared__ __align__(16) uint16_t As[128][40];   // pad 8 bf16 = 16B; rowstride 80B
    __shared__ __align__(16) uint16_t Bs[128][40];
    const int bm = blockIdx.y, bn = blockIdx.x;
    const int t = threadIdx.x;
    const int w = t >> 6, lane = t & 63;
    const int wy = w >> 1, wx = w & 1;
    const int q = lane >> 4, r = lane & 15;

    floatx4 acc[4][4];
#pragma unroll
    for (int i = 0; i < 4; ++i)
#pragma unroll
        for (int j = 0; j < 4; ++j)
            acc[i][j] = (floatx4){0.f, 0.f, 0.f, 0.f};

    const size_t abase = (size_t)(bm * 128) * K;
    const size_t bbase = (size_t)(bn * 128) * K;

    for (int k0 = 0; k0 < K; k0 += 32) {
#pragma unroll
        for (int s = 0; s < 2; ++s) {
            int c = t + s * 256;
            int row = c >> 2, col = (c & 3) * 8;
            *(uint4*)&As[row][col] = *(const uint4*)(A + abase + (size_t)row * K + k0 + col);
            *(uint4*)&Bs[row][col] = *(const uint4*)(Bt + bbase + (size_t)row * K + k0 + col);
        }
        __syncthreads();
        bf16x8 fa[4], fb[4];
#pragma unroll
        for (int i = 0; i < 4; ++i) fa[i] = *(const bf16x8*)&As[wy * 64 + i * 16 + r][q * 8];
#pragma unroll
        for (int j = 0; j < 4; ++j) fb[j] = *(const bf16x8*)&Bs[wx * 64 + j * 16 + r][q * 8];
#pragma unroll
        for (int i = 0; i < 4; ++i)
#pragma unroll
            for (int j = 0; j < 4; ++j)
                acc[i][j] = __builtin_amdgcn_mfma_f32_16x16x32_bf16(fa[i], fb[j], acc[i][j], 0, 0, 0);
        __syncthreads();
    }

#pragma unroll
    for (int i = 0; i < 4; ++i) {
#pragma unroll
        for (int j = 0; j < 4; ++j) {
#pragma unroll
            for (int e = 0; e < 4; ++e) {
                int m = bm * 128 + wy * 64 + i * 16 + q * 4 + e;
                int n = bn * 128 + wx * 64 + j * 16 + r;
                float v = acc[i][j][e];
                if (bias) v += bias[n];
                if (EPI == EPI_GELU) v = 0.5f * v * (1.f + erff(v * 0.70710678118f));
                if (EPI == EPI_BF16 || EPI == EPI_GELU) {
                    Cbf[(size_t)m * N + n] = f2bf(v);
                } else if (EPI == EPI_RESID) {
                    Cf[(size_t)m * N + n] += v;
                } else {
                    if (n < Nstore) Cf[(size_t)m * Nstore + n] = v;
                }
            }
        }
    }
}

// ---------------------------------------------------------------------------
// Flash-style MFMA attention. One workgroup per (b, h, 64-query block).
// 4 waves, each owns 16 query rows. KV tiles of 64 keys staged in LDS:
//   Ks [64 keys][64+8 dims]  (row-major; B-operand for QK^T)
//   Vt [64 dims][64+8 keys]  (transposed; B-operand for PV)
// S computed by mfma_f32_16x16x32_bf16 (D layout: row=(lane>>4)*4+e, col=lane&15),
// online softmax in registers (row reduce over the 16-lane group via shfl_xor),
// P converted to bf16 through per-wave LDS (D-layout -> A-layout), PV by MFMA.
// qkv bf16 [2048, 2304] (q|k|v each 768, head-major 64). y bf16 [2048,768].
// ---------------------------------------------------------------------------
__global__ __launch_bounds__(256) void fattn_kernel(const uint16_t* __restrict__ qkv,
                                                    uint16_t* __restrict__ y) {
    __shared__ __align__(16) uint16_t Ks[64][72];     // +8 pad: rowstride 144B
    __shared__ __align__(16) uint16_t Vt[64][72];
    __shared__ __align__(16) uint16_t Pl[4][16][72];  // per-wave P buffer

    const int t = threadIdx.x;
    const int w = t >> 6, lane = t & 63;
    const int q = lane >> 4, r = lane & 15;
    const int bh = blockIdx.x;                 // 0..23
    const int qb = 15 - blockIdx.y;            // largest blocks dispatched first
    const int b_ = bh / 12, h = bh - b_ * 12;
    const int qrow0 = qb * 64 + w * 16;        // wave's first query row

    // Q fragments (A-operand), held for the whole kernel.
    bf16x8 fq0, fq1;
    {
        const uint16_t* qp = qkv + ((size_t)(b_ * 1024 + qrow0 + r)) * 2304 + h * 64 + q * 8;
        fq0 = *(const bf16x8*)qp;
        fq1 = *(const bf16x8*)(qp + 32);
    }

    floatx4 o[4];
    float m_[4], l_[4];
#pragma unroll
    for (int jt = 0; jt < 4; ++jt) o[jt] = (floatx4){0.f, 0.f, 0.f, 0.f};
#pragma unroll
    for (int e = 0; e < 4; ++e) { m_[e] = -INFINITY; l_[e] = 0.f; }

    for (int kb = 0; kb <= qb; ++kb) {
        const int kv0 = kb * 64;
        // ---- stage K (row-major) and V (transposed, bank-staggered) ----
#pragma unroll
        for (int s = 0; s < 2; ++s) {
            int c = t + s * 256;               // 0..511
            int row = c >> 3;                  // key within tile
            int col = (c & 7) * 8;             // dim base
            const uint16_t* kp = qkv + ((size_t)(b_ * 1024 + kv0 + row)) * 2304
                                 + 768 + h * 64 + col;
            *(uint4*)&Ks[row][col] = *(const uint4*)kp;
            uint16_t __attribute__((aligned(16))) tmp[8];
            *(uint4*)tmp = *(const uint4*)(kp + 768);   // V same row, +768
#pragma unroll
            for (int j0 = 0; j0 < 8; ++j0) {
                int j = (j0 + t) & 7;          // stagger to spread banks
                Vt[col + j][row] = tmp[j];
            }
        }
        __syncthreads();

        // ---- S = Q K^T : 16x64 per wave via 8 MFMAs ----
        floatx4 s4[4];
#pragma unroll
        for (int j = 0; j < 4; ++j) s4[j] = (floatx4){0.f, 0.f, 0.f, 0.f};
#pragma unroll
        for (int ks = 0; ks < 2; ++ks) {
            bf16x8 fa = ks ? fq1 : fq0;
#pragma unroll
            for (int j = 0; j < 4; ++j) {
                bf16x8 fk = *(const bf16x8*)&Ks[j * 16 + r][ks * 32 + q * 8];
                s4[j] = __builtin_amdgcn_mfma_f32_16x16x32_bf16(fa, fk, s4[j], 0, 0, 0);
            }
        }

        // ---- online softmax (rows = q*4+e, cols spread over 16-lane group) ----
        const bool diag = (kb == qb);
#pragma unroll
        for (int e = 0; e < 4; ++e) {
            float v[4];
#pragma unroll
            for (int j = 0; j < 4; ++j) v[j] = s4[j][e] * 0.125f;  // 1/sqrt(64)
            if (diag) {
                int qi = w * 16 + q * 4 + e;    // local query index in block
#pragma unroll
                for (int j = 0; j < 4; ++j)
                    if (j * 16 + r > qi) v[j] = -INFINITY;
            }
            float rm = fmaxf(fmaxf(v[0], v[1]), fmaxf(v[2], v[3]));
#pragma unroll
            for (int mk = 1; mk <= 8; mk <<= 1) rm = fmaxf(rm, __shfl_xor(rm, mk, 64));
            float mn = fmaxf(m_[e], rm);
            float al = __expf(m_[e] - mn);      // 0 on first tile (m_=-inf)
            float p[4], rsum = 0.f;
#pragma unroll
            for (int j = 0; j < 4; ++j) { p[j] = __expf(v[j] - mn); rsum += p[j]; }
#pragma unroll
            for (int mk = 1; mk <= 8; mk <<= 1) rsum += __shfl_xor(rsum, mk, 64);
            l_[e] = l_[e] * al + rsum;
            m_[e] = mn;
#pragma unroll
            for (int jt = 0; jt < 4; ++jt) o[jt][e] *= al;
#pragma unroll
            for (int j = 0; j < 4; ++j) Pl[w][q * 4 + e][j * 16 + r] = f2bf(p[j]);
        }
        // Pl is wave-private: in-wave write->read needs only an LDS drain.
        asm volatile("s_waitcnt lgkmcnt(0)" ::: "memory");

        // ---- O += P V : 8 MFMAs ----
#pragma unroll
        for (int ks = 0; ks < 2; ++ks) {
            bf16x8 pa = *(const bf16x8*)&Pl[w][r][ks * 32 + q * 8];
#pragma unroll
            for (int jt = 0; jt < 4; ++jt) {
                bf16x8 vb = *(const bf16x8*)&Vt[jt * 16 + r][ks * 32 + q * 8];
                o[jt] = __builtin_amdgcn_mfma_f32_16x16x32_bf16(pa, vb, o[jt], 0, 0, 0);
            }
        }
        __syncthreads();   // protect Ks/Vt before next tile's staging
    }

    // ---- epilogue: y = O / l ----
    uint16_t* yrow = y + ((size_t)(b_ * 1024 + qrow0)) * 768 + h * 64;
#pragma unroll
    for (int e = 0; e < 4; ++e) {
        float inv = 1.f / l_[e];
        int qi = q * 4 + e;
#pragma unroll
        for (int jt = 0; jt < 4; ++jt)
            yrow[(size_t)qi * 768 + jt * 16 + r] = f2bf(o[jt][e] * inv);
    }
}

// ---------------------------------------------------------------------------
extern "C" void kernel_launch(void* const* d_in, const int* in_sizes, int n_in,
                              void* d_out, int out_size, void* d_ws, size_t ws_size,
                              hipStream_t stream) {
    (void)in_sizes; (void)n_in; (void)out_size; (void)ws_size;
    const int*   idx    = (const int*)  d_in[0];
    const float* wte    = (const float*)d_in[1];
    const float* wpe    = (const float*)d_in[2];
    const float* ln1_g  = (const float*)d_in[3];
    const float* ln1_b  = (const float*)d_in[4];
    const float* w_attn = (const float*)d_in[5];
    const float* b_attn = (const float*)d_in[6];
    const float* w_ap   = (const float*)d_in[7];
    const float* b_ap   = (const float*)d_in[8];
    const float* ln2_g  = (const float*)d_in[9];
    const float* ln2_b  = (const float*)d_in[10];
    const float* w_fc   = (const float*)d_in[11];
    const float* b_fc   = (const float*)d_in[12];
    const float* w_mp   = (const float*)d_in[13];
    const float* b_mp   = (const float*)d_in[14];
    const float* lnf_g  = (const float*)d_in[15];
    const float* lnf_b  = (const float*)d_in[16];
    const float* w_head = (const float*)d_in[17];
    float* out = (float*)d_out;

    char* p = (char*)d_ws;
    auto take = [&](size_t bytes) -> char* {
        char* r = p; p += (bytes + 255) & ~(size_t)255; return r;
    };
    float*    x     = (float*)   take((size_t)2048 * 768 * 4);
    uint16_t* h     = (uint16_t*)take((size_t)2048 * 768 * 2);
    uint16_t* qkv   = (uint16_t*)take((size_t)2048 * 2304 * 2);
    uint16_t* y     = (uint16_t*)take((size_t)2048 * 768 * 2);
    uint16_t* fca   = (uint16_t*)take((size_t)2048 * 3072 * 2);
    uint16_t* attnT = (uint16_t*)take((size_t)4 * 2304 * 768 * 2);
    uint16_t* apT   = (uint16_t*)take((size_t)4 * 768 * 768 * 2);
    uint16_t* fcT   = (uint16_t*)take((size_t)4 * 3072 * 768 * 2);
    uint16_t* mpT   = (uint16_t*)take((size_t)4 * 768 * 3072 * 2);
    uint16_t* headT = (uint16_t*)take((size_t)50304 * 768 * 2);

    dim3 tb(32, 8);
    transpose_cvt<<<dim3(2304 / 32, 768 / 32, 4), tb, 0, stream>>>(
        w_attn, attnT, 768, 2304, (size_t)768 * 2304, (size_t)2304 * 768);
    transpose_cvt<<<dim3(768 / 32, 768 / 32, 4), tb, 0, stream>>>(
        w_ap, apT, 768, 768, (size_t)768 * 768, (size_t)768 * 768);
    transpose_cvt<<<dim3(3072 / 32, 768 / 32, 4), tb, 0, stream>>>(
        w_fc, fcT, 768, 3072, (size_t)768 * 3072, (size_t)3072 * 768);
    transpose_cvt<<<dim3(768 / 32, 3072 / 32, 4), tb, 0, stream>>>(
        w_mp, mpT, 3072, 768, (size_t)3072 * 768, (size_t)768 * 3072);
    transpose_cvt<<<dim3(50304 / 32, 768 / 32, 1), tb, 0, stream>>>(
        w_head, headT, 768, 50257, 0, 0);

    embed_kernel<<<6144, 256, 0, stream>>>(idx, wte, wpe, x);

    for (int l = 0; l < 4; ++l) {
        ln_kernel<<<2048, 256, 0, stream>>>(x, ln1_g + l * 768, ln1_b + l * 768, h);
        gemm128<EPI_BF16><<<dim3(2304 / 128, 16), 256, 0, stream>>>(
            h, attnT + (size_t)l * 2304 * 768, b_attn + l * 2304, qkv, nullptr,
            2048, 2304, 768, 2304);
        fattn_kernel<<<dim3(24, 16), 256, 0, stream>>>(qkv, y);
        gemm128<EPI_RESID><<<dim3(768 / 128, 16), 256, 0, stream>>>(
            y, apT + (size_t)l * 768 * 768, b_ap + l * 768, nullptr, x,
            2048, 768, 768, 768);
        ln_kernel<<<2048, 256, 0, stream>>>(x, ln2_g + l * 768, ln2_b + l * 768, h);
        gemm128<EPI_GELU><<<dim3(3072 / 128, 16), 256, 0, stream>>>(
            h, fcT + (size_t)l * 3072 * 768, b_fc + l * 3072, fca, nullptr,
            2048, 3072, 768, 3072);
        gemm128<EPI_RESID><<<dim3(768 / 128, 16), 256, 0, stream>>>(
            fca, mpT + (size_t)l * 768 * 3072, b_mp + l * 768, nullptr, x,
            2048, 768, 3072, 768);
    }
    ln_kernel<<<2048, 256, 0, stream>>>(x, lnf_g, lnf_b, h);
    gemm128<EPI_F32><<<dim3(50304 / 128, 16), 256, 0, stream>>>(
        h, headT, nullptr, nullptr, out, 2048, 50304, 768, 50257);
}

// Round 3
// 1808.070 us; speedup vs baseline: 2.2808x; 1.1066x over previous
//
#include <hip/hip_runtime.h>
#include <hip/hip_bf16.h>
#include <cstdint>
#include <cstddef>

// ---------------------------------------------------------------------------
// GPT-2 forward (L=4, B=2, T=1024, C=768, H=12, V=50257) on gfx950.
// Strategy: bf16 MFMA GEMMs (fp32 accum, global_load_lds staging, XCD-aware
// block remap, split-K for small-N residual GEMMs), fp32 residual stream,
// flash-style MFMA attention with online softmax.
// ---------------------------------------------------------------------------

typedef __bf16 bf16x8 __attribute__((ext_vector_type(8)));
typedef float floatx4 __attribute__((ext_vector_type(4)));

__device__ inline float bf2f(uint16_t h) {
    union { uint32_t u; float f; } x; x.u = ((uint32_t)h) << 16; return x.f;
}
__device__ inline uint16_t f2bf(float f) {
    union { float f; uint32_t u; } x; x.f = f;
    uint32_t u = x.u;
    uint32_t r = (u + 0x7fffu + ((u >> 16) & 1u)) >> 16;   // RNE
    return (uint16_t)r;
}

// Async global->LDS, 16B per lane. LDS dest must be wave-uniform; HW writes
// lds + lane*16 (so LDS layout must be linear in lane order).
__device__ inline void gload_lds16(const uint16_t* __restrict__ g, uint16_t* l) {
    __builtin_amdgcn_global_load_lds(
        (const __attribute__((address_space(1))) void*)(const void*)g,
        (__attribute__((address_space(3))) void*)(void*)l,
        16, 0, 0);
}

// ---------------------------------------------------------------------------
// Weight transpose + fp32->bf16 convert: in fp32 [K,N] -> out bf16 [Npad,K].
// Zero-fills n in [N, Npad). blockIdx.z = layer.
// ---------------------------------------------------------------------------
__global__ void transpose_cvt(const float* __restrict__ in, uint16_t* __restrict__ out,
                              int K, int N, size_t in_lstride, size_t out_lstride) {
    __shared__ float tile[32][33];
    in  += (size_t)blockIdx.z * in_lstride;
    out += (size_t)blockIdx.z * out_lstride;
    int n0 = blockIdx.x * 32, k0 = blockIdx.y * 32;
    int tx = threadIdx.x, ty = threadIdx.y;
#pragma unroll
    for (int i = 0; i < 4; ++i) {
        int k = k0 + ty + i * 8;
        int n = n0 + tx;
        tile[ty + i * 8][tx] = (n < N) ? in[(size_t)k * N + n] : 0.f;
    }
    __syncthreads();
#pragma unroll
    for (int i = 0; i < 4; ++i) {
        int n = n0 + ty + i * 8;
        int k = k0 + tx;
        out[(size_t)n * K + k] = f2bf(tile[tx][ty + i * 8]);
    }
}

// ---------------------------------------------------------------------------
// Embedding: x[row,c] = wte[idx[row],c] + wpe[row%1024,c]   (fp32)
// ---------------------------------------------------------------------------
__global__ void embed_kernel(const int* __restrict__ idx, const float* __restrict__ wte,
                             const float* __restrict__ wpe, float* __restrict__ x) {
    int tid = blockIdx.x * 256 + threadIdx.x;      // 2048*768 total
    int row = tid / 768, c = tid - row * 768;
    int t = row & 1023;
    int tok = idx[row];
    x[tid] = wte[(size_t)tok * 768 + c] + wpe[(size_t)t * 768 + c];
}

// ---------------------------------------------------------------------------
// LayerNorm: fp32 [row,768] -> bf16 out. One block (256 thr) per row.
// ---------------------------------------------------------------------------
__global__ __launch_bounds__(256) void ln_kernel(const float* __restrict__ x,
                                                 const float* __restrict__ g,
                                                 const float* __restrict__ beta,
                                                 uint16_t* __restrict__ out) {
    int row = blockIdx.x;
    int t = threadIdx.x;
    int w = t >> 6, lane = t & 63;
    const float* xr = x + (size_t)row * 768;
    float v0 = xr[t], v1 = xr[t + 256], v2 = xr[t + 512];
    float s = v0 + v1 + v2;
    float s2 = v0 * v0 + v1 * v1 + v2 * v2;
#pragma unroll
    for (int mk = 32; mk >= 1; mk >>= 1) {
        s += __shfl_xor(s, mk, 64);
        s2 += __shfl_xor(s2, mk, 64);
    }
    __shared__ float rs[4], rq[4];
    if (lane == 0) { rs[w] = s; rq[w] = s2; }
    __syncthreads();
    float S = rs[0] + rs[1] + rs[2] + rs[3];
    float S2 = rq[0] + rq[1] + rq[2] + rq[3];
    float mean = S * (1.f / 768.f);
    float var = S2 * (1.f / 768.f) - mean * mean;
    float rinv = rsqrtf(var + 1e-5f);
    uint16_t* orow = out + (size_t)row * 768;
    orow[t]       = f2bf((v0 - mean) * rinv * g[t]       + beta[t]);
    orow[t + 256] = f2bf((v1 - mean) * rinv * g[t + 256] + beta[t + 256]);
    orow[t + 512] = f2bf((v2 - mean) * rinv * g[t + 512] + beta[t + 512]);
}

// ---------------------------------------------------------------------------
// GEMM: C[M,N] = A[M,K](bf16) @ Bt[N,K](bf16, pre-transposed) + bias.
// 128x128 tile, BK=32, 4 waves (2x2), 64x64 per wave via 4x4 mfma 16x16x32.
// Staging via global_load_lds width=16 (m97 pattern): linear LDS [128][32].
// Block remap: bm varies fastest within a per-XCD contiguous chunk of bn
// panels (assumes dispatch round-robins XCDs; requires gridDim.x*16 % 8 == 0,
// true for all launches here). Split-K via gridDim.z for EPI_RESID (atomic).
// Epilogues: 0=bf16 store, 1=gelu+bf16, 2=residual fp32 atomicAdd, 3=fp32
// store (n<Nstore).
// ---------------------------------------------------------------------------
enum { EPI_BF16 = 0, EPI_GELU = 1, EPI_RESID = 2, EPI_F32 = 3 };

template <int EPI>
__global__ __launch_bounds__(256, 2)
void gemm128(const uint16_t* __restrict__ A, const uint16_t* __restrict__ Bt,
             const float* __restrict__ bias, uint16_t* __restrict__ Cbf,
             float* __restrict__ Cf, int M, int N, int K, int Nstore) {
    __shared__ __align__(16) uint16_t As[128][32];   // linear: global_load_lds dest
    __shared__ __align__(16) uint16_t Bs[128][32];
    const int t = threadIdx.x;
    const int w = t >> 6, lane = t & 63;
    const int wy = w >> 1, wx = w & 1;
    const int q = lane >> 4, r = lane & 15;

    // XCD-locality remap (bijective; nwg % 8 == 0 since gridDim.y == 16).
    const int nbn = gridDim.x;
    const int flat = blockIdx.y * nbn + blockIdx.x;
    const int per = (nbn * 16) >> 3;
    const int virt = (flat & 7) * per + (flat >> 3);
    const int bm = virt & 15;
    const int bn = virt >> 4;

    // K slice (split-K): slice size = K / gridDim.z, multiple of 32 here.
    const int ksl = K / (int)gridDim.z;
    const int k_beg = (int)blockIdx.z * ksl;
    const int k_end = k_beg + ksl;

    floatx4 acc[4][4];
#pragma unroll
    for (int i = 0; i < 4; ++i)
#pragma unroll
        for (int j = 0; j < 4; ++j)
            acc[i][j] = (floatx4){0.f, 0.f, 0.f, 0.f};

    const size_t abase = (size_t)(bm * 128) * K;
    const size_t bbase = (size_t)(bn * 128) * K;
    const int srow = lane >> 2;          // 0..15: row within 16-row region
    const int scol = (lane & 3) * 8;     // 0,8,16,24

    for (int k0 = k_beg; k0 < k_end; k0 += 32) {
        // Each wave stages A rows [w*32, w*32+32) and same B rows: 2 calls each.
#pragma unroll
        for (int c = 0; c < 2; ++c) {
            int row = w * 32 + c * 16 + srow;
            gload_lds16(A + abase + (size_t)row * K + k0 + scol, &As[w * 32 + c * 16][0]);
            gload_lds16(Bt + bbase + (size_t)row * K + k0 + scol, &Bs[w * 32 + c * 16][0]);
        }
        asm volatile("s_waitcnt vmcnt(0)" ::: "memory");
        __syncthreads();
        bf16x8 fa[4], fb[4];
#pragma unroll
        for (int i = 0; i < 4; ++i) fa[i] = *(const bf16x8*)&As[wy * 64 + i * 16 + r][q * 8];
#pragma unroll
        for (int j = 0; j < 4; ++j) fb[j] = *(const bf16x8*)&Bs[wx * 64 + j * 16 + r][q * 8];
#pragma unroll
        for (int i = 0; i < 4; ++i)
#pragma unroll
            for (int j = 0; j < 4; ++j)
                acc[i][j] = __builtin_amdgcn_mfma_f32_16x16x32_bf16(fa[i], fb[j], acc[i][j], 0, 0, 0);
        __syncthreads();
    }

#pragma unroll
    for (int i = 0; i < 4; ++i) {
#pragma unroll
        for (int j = 0; j < 4; ++j) {
#pragma unroll
            for (int e = 0; e < 4; ++e) {
                int m = bm * 128 + wy * 64 + i * 16 + q * 4 + e;
                int n = bn * 128 + wx * 64 + j * 16 + r;
                float v = acc[i][j][e];
                if (bias && blockIdx.z == 0) v += bias[n];
                if (EPI == EPI_GELU) v = 0.5f * v * (1.f + erff(v * 0.70710678118f));
                if (EPI == EPI_BF16 || EPI == EPI_GELU) {
                    Cbf[(size_t)m * N + n] = f2bf(v);
                } else if (EPI == EPI_RESID) {
                    atomicAdd(&Cf[(size_t)m * N + n], v);
                } else {
                    if (n < Nstore) Cf[(size_t)m * Nstore + n] = v;
                }
            }
        }
    }
}

// ---------------------------------------------------------------------------
// Flash-style MFMA attention. One workgroup per (b, h, 64-query block).
// 4 waves, each owns 16 query rows. KV tiles of 64 keys staged in LDS.
// ---------------------------------------------------------------------------
__global__ __launch_bounds__(256) void fattn_kernel(const uint16_t* __restrict__ qkv,
                                                    uint16_t* __restrict__ y) {
    __shared__ __align__(16) uint16_t Ks[64][72];     // +8 pad: rowstride 144B
    __shared__ __align__(16) uint16_t Vt[64][72];
    __shared__ __align__(16) uint16_t Pl[4][16][72];  // per-wave P buffer

    const int t = threadIdx.x;
    const int w = t >> 6, lane = t & 63;
    const int q = lane >> 4, r = lane & 15;
    const int bh = blockIdx.x;                 // 0..23
    const int qb = 15 - blockIdx.y;            // largest blocks dispatched first
    const int b_ = bh / 12, h = bh - b_ * 12;
    const int qrow0 = qb * 64 + w * 16;        // wave's first query row

    // Q fragments (A-operand), held for the whole kernel.
    bf16x8 fq0, fq1;
    {
        const uint16_t* qp = qkv + ((size_t)(b_ * 1024 + qrow0 + r)) * 2304 + h * 64 + q * 8;
        fq0 = *(const bf16x8*)qp;
        fq1 = *(const bf16x8*)(qp + 32);
    }

    floatx4 o[4];
    float m_[4], l_[4];
#pragma unroll
    for (int jt = 0; jt < 4; ++jt) o[jt] = (floatx4){0.f, 0.f, 0.f, 0.f};
#pragma unroll
    for (int e = 0; e < 4; ++e) { m_[e] = -INFINITY; l_[e] = 0.f; }

    for (int kb = 0; kb <= qb; ++kb) {
        const int kv0 = kb * 64;
        // ---- stage K (row-major) and V (transposed, bank-staggered) ----
#pragma unroll
        for (int s = 0; s < 2; ++s) {
            int c = t + s * 256;               // 0..511
            int row = c >> 3;                  // key within tile
            int col = (c & 7) * 8;             // dim base
            const uint16_t* kp = qkv + ((size_t)(b_ * 1024 + kv0 + row)) * 2304
                                 + 768 + h * 64 + col;
            *(uint4*)&Ks[row][col] = *(const uint4*)kp;
            uint16_t __attribute__((aligned(16))) tmp[8];
            *(uint4*)tmp = *(const uint4*)(kp + 768);   // V same row, +768
#pragma unroll
            for (int j0 = 0; j0 < 8; ++j0) {
                int j = (j0 + t) & 7;          // stagger to spread banks
                Vt[col + j][row] = tmp[j];
            }
        }
        __syncthreads();

        // ---- S = Q K^T : 16x64 per wave via 8 MFMAs ----
        floatx4 s4[4];
#pragma unroll
        for (int j = 0; j < 4; ++j) s4[j] = (floatx4){0.f, 0.f, 0.f, 0.f};
#pragma unroll
        for (int ks = 0; ks < 2; ++ks) {
            bf16x8 fa = ks ? fq1 : fq0;
#pragma unroll
            for (int j = 0; j < 4; ++j) {
                bf16x8 fk = *(const bf16x8*)&Ks[j * 16 + r][ks * 32 + q * 8];
                s4[j] = __builtin_amdgcn_mfma_f32_16x16x32_bf16(fa, fk, s4[j], 0, 0, 0);
            }
        }

        // ---- online softmax (rows = q*4+e, cols spread over 16-lane group) ----
        const bool diag = (kb == qb);
#pragma unroll
        for (int e = 0; e < 4; ++e) {
            float v[4];
#pragma unroll
            for (int j = 0; j < 4; ++j) v[j] = s4[j][e] * 0.125f;  // 1/sqrt(64)
            if (diag) {
                int qi = w * 16 + q * 4 + e;    // local query index in block
#pragma unroll
                for (int j = 0; j < 4; ++j)
                    if (j * 16 + r > qi) v[j] = -INFINITY;
            }
            float rm = fmaxf(fmaxf(v[0], v[1]), fmaxf(v[2], v[3]));
#pragma unroll
            for (int mk = 1; mk <= 8; mk <<= 1) rm = fmaxf(rm, __shfl_xor(rm, mk, 64));
            float mn = fmaxf(m_[e], rm);
            float al = __expf(m_[e] - mn);      // 0 on first tile (m_=-inf)
            float p[4], rsum = 0.f;
#pragma unroll
            for (int j = 0; j < 4; ++j) { p[j] = __expf(v[j] - mn); rsum += p[j]; }
#pragma unroll
            for (int mk = 1; mk <= 8; mk <<= 1) rsum += __shfl_xor(rsum, mk, 64);
            l_[e] = l_[e] * al + rsum;
            m_[e] = mn;
#pragma unroll
            for (int jt = 0; jt < 4; ++jt) o[jt][e] *= al;
#pragma unroll
            for (int j = 0; j < 4; ++j) Pl[w][q * 4 + e][j * 16 + r] = f2bf(p[j]);
        }
        // Pl is wave-private: in-wave write->read needs only an LDS drain.
        asm volatile("s_waitcnt lgkmcnt(0)" ::: "memory");

        // ---- O += P V : 8 MFMAs ----
#pragma unroll
        for (int ks = 0; ks < 2; ++ks) {
            bf16x8 pa = *(const bf16x8*)&Pl[w][r][ks * 32 + q * 8];
#pragma unroll
            for (int jt = 0; jt < 4; ++jt) {
                bf16x8 vb = *(const bf16x8*)&Vt[jt * 16 + r][ks * 32 + q * 8];
                o[jt] = __builtin_amdgcn_mfma_f32_16x16x32_bf16(pa, vb, o[jt], 0, 0, 0);
            }
        }
        __syncthreads();   // protect Ks/Vt before next tile's staging
    }

    // ---- epilogue: y = O / l ----
    uint16_t* yrow = y + ((size_t)(b_ * 1024 + qrow0)) * 768 + h * 64;
#pragma unroll
    for (int e = 0; e < 4; ++e) {
        float inv = 1.f / l_[e];
        int qi = q * 4 + e;
#pragma unroll
        for (int jt = 0; jt < 4; ++jt)
            yrow[(size_t)qi * 768 + jt * 16 + r] = f2bf(o[jt][e] * inv);
    }
}

// ---------------------------------------------------------------------------
extern "C" void kernel_launch(void* const* d_in, const int* in_sizes, int n_in,
                              void* d_out, int out_size, void* d_ws, size_t ws_size,
                              hipStream_t stream) {
    (void)in_sizes; (void)n_in; (void)out_size; (void)ws_size;
    const int*   idx    = (const int*)  d_in[0];
    const float* wte    = (const float*)d_in[1];
    const float* wpe    = (const float*)d_in[2];
    const float* ln1_g  = (const float*)d_in[3];
    const float* ln1_b  = (const float*)d_in[4];
    const float* w_attn = (const float*)d_in[5];
    const float* b_attn = (const float*)d_in[6];
    const float* w_ap   = (const float*)d_in[7];
    const float* b_ap   = (const float*)d_in[8];
    const float* ln2_g  = (const float*)d_in[9];
    const float* ln2_b  = (const float*)d_in[10];
    const float* w_fc   = (const float*)d_in[11];
    const float* b_fc   = (const float*)d_in[12];
    const float* w_mp   = (const float*)d_in[13];
    const float* b_mp   = (const float*)d_in[14];
    const float* lnf_g  = (const float*)d_in[15];
    const float* lnf_b  = (const float*)d_in[16];
    const float* w_head = (const float*)d_in[17];
    float* out = (float*)d_out;

    char* p = (char*)d_ws;
    auto take = [&](size_t bytes) -> char* {
        char* r = p; p += (bytes + 255) & ~(size_t)255; return r;
    };
    float*    x     = (float*)   take((size_t)2048 * 768 * 4);
    uint16_t* h     = (uint16_t*)take((size_t)2048 * 768 * 2);
    uint16_t* qkv   = (uint16_t*)take((size_t)2048 * 2304 * 2);
    uint16_t* y     = (uint16_t*)take((size_t)2048 * 768 * 2);
    uint16_t* fca   = (uint16_t*)take((size_t)2048 * 3072 * 2);
    uint16_t* attnT = (uint16_t*)take((size_t)4 * 2304 * 768 * 2);
    uint16_t* apT   = (uint16_t*)take((size_t)4 * 768 * 768 * 2);
    uint16_t* fcT   = (uint16_t*)take((size_t)4 * 3072 * 768 * 2);
    uint16_t* mpT   = (uint16_t*)take((size_t)4 * 768 * 3072 * 2);
    uint16_t* headT = (uint16_t*)take((size_t)50304 * 768 * 2);

    dim3 tb(32, 8);
    transpose_cvt<<<dim3(2304 / 32, 768 / 32, 4), tb, 0, stream>>>(
        w_attn, attnT, 768, 2304, (size_t)768 * 2304, (size_t)2304 * 768);
    transpose_cvt<<<dim3(768 / 32, 768 / 32, 4), tb, 0, stream>>>(
        w_ap, apT, 768, 768, (size_t)768 * 768, (size_t)768 * 768);
    transpose_cvt<<<dim3(3072 / 32, 768 / 32, 4), tb, 0, stream>>>(
        w_fc, fcT, 768, 3072, (size_t)768 * 3072, (size_t)3072 * 768);
    transpose_cvt<<<dim3(768 / 32, 3072 / 32, 4), tb, 0, stream>>>(
        w_mp, mpT, 3072, 768, (size_t)3072 * 768, (size_t)768 * 3072);
    transpose_cvt<<<dim3(50304 / 32, 768 / 32, 1), tb, 0, stream>>>(
        w_head, headT, 768, 50257, 0, 0);

    embed_kernel<<<6144, 256, 0, stream>>>(idx, wte, wpe, x);

    for (int l = 0; l < 4; ++l) {
        ln_kernel<<<2048, 256, 0, stream>>>(x, ln1_g + l * 768, ln1_b + l * 768, h);
        gemm128<EPI_BF16><<<dim3(2304 / 128, 16), 256, 0, stream>>>(
            h, attnT + (size_t)l * 2304 * 768, b_attn + l * 2304, qkv, nullptr,
            2048, 2304, 768, 2304);
        fattn_kernel<<<dim3(24, 16), 256, 0, stream>>>(qkv, y);
        gemm128<EPI_RESID><<<dim3(768 / 128, 16, 2), 256, 0, stream>>>(
            y, apT + (size_t)l * 768 * 768, b_ap + l * 768, nullptr, x,
            2048, 768, 768, 768);
        ln_kernel<<<2048, 256, 0, stream>>>(x, ln2_g + l * 768, ln2_b + l * 768, h);
        gemm128<EPI_GELU><<<dim3(3072 / 128, 16), 256, 0, stream>>>(
            h, fcT + (size_t)l * 3072 * 768, b_fc + l * 3072, fca, nullptr,
            2048, 3072, 768, 3072);
        gemm128<EPI_RESID><<<dim3(768 / 128, 16, 4), 256, 0, stream>>>(
            fca, mpT + (size_t)l * 768 * 3072, b_mp + l * 768, nullptr, x,
            2048, 768, 3072, 768);
    }
    ln_kernel<<<2048, 256, 0, stream>>>(x, lnf_g, lnf_b, h);
    gemm128<EPI_F32><<<dim3(50304 / 128, 16), 256, 0, stream>>>(
        h, headT, nullptr, nullptr, out, 2048, 50304, 768, 50257);
}